// Round 3
// baseline (270.041 us; speedup 1.0000x reference)
//
#include <hip/hip_runtime.h>

// Problem shape (fixed by setup_inputs): B=2, C=4, D=128, H=192, W=192
#define NB 2
#define NS (128 * 192 * 192)      // spatial voxels per batch = 4718592
#define NTOT (NB * NS)            // 9437184
#define NSQ (NS / 4)              // float4-quads per batch = 1179648
#define EPSF 1e-8f
#define INF_BITS 0x7F800000u

// R11 geometry: 1024 blocks = 4 blocks/CU (single residency round at 4
// waves/SIMD with VGPR<=128 -> no half-occupancy tail round).
#define TPB 256
#define BPB 512                    // blocks per batch
#define BLOCKS (2 * BPB)           // 1024
#define STRIDE (BPB * TPB)         // 131072 quads per sweep
#define ITERS (NSQ / STRIDE)       // exactly 9

// Decomposition: loss = -(R0 + sum_{b,j} s_bj*(P_bj - mn_bj*Q_bj)) / NTOT
//   P_bj = sum z_j*(a_j-lse), Q_bj = sum (a_j-lse), R0 = sum (t==0)*(a_0-lse)
// part layout: 16 floats per block: [0..2]=mn [3..5]=mx [6..8]=P [9..11]=Q [12]=R0

typedef float __attribute__((ext_vector_type(4))) f32x4;
typedef int   __attribute__((ext_vector_type(4))) i32x4;

// R11 (resubmit after broker timeout): R10 counters showed k_fused
// latency-bound (HBM 16%, VALU 18%, 2.56 TB/s effective vs 6.3+ achievable)
// with VGPR squeezed to 64 by the waves_per_eu(2,6) cap -- the A/B double
// buffer (48 data VGPRs + 13 acc + 6x 64-bit address chains) cannot be fully
// live in 64 regs, so the compiler serialized the loads. Fix:
// waves_per_eu(2,4) (<=128 VGPR), TRIPLE buffer (18 loads in flight per
// wave), and single int byte-offset vs 6 uniform SGPR base pointers.
__global__ __launch_bounds__(TPB)
__attribute__((amdgpu_waves_per_eu(2, 4)))
void k_fused(const float* __restrict__ x,
             const int* __restrict__ tgt,
             const float* __restrict__ dist,
             float* __restrict__ part) {
    const int b = (blockIdx.x >= BPB) ? 1 : 0;
    const int bid = blockIdx.x - b * BPB;
    const int q0 = bid * TPB + threadIdx.x;

    // Uniform byte bases for the 6 streams (SGPR pairs); per-thread offset is
    // a single 32-bit int -> global_load_dwordx4 v, v_off, s[base].
    const char* xb0 = (const char*)x + (size_t)b * 4 * NSQ * 16;
    const char* xb1 = xb0 + (size_t)NSQ * 16;
    const char* xb2 = xb0 + (size_t)NSQ * 32;
    const char* xb3 = xb0 + (size_t)NSQ * 48;
    const char* tb0 = (const char*)tgt + (size_t)b * NSQ * 16;
    const char* db0 = (const char*)dist + (size_t)b * NSQ * 16;

    float mn1 = __uint_as_float(INF_BITS), mn2 = mn1, mn3 = mn1;
    float mx1 = 0.f, mx2 = 0.f, mx3 = 0.f;
    float P1 = 0.f, P2 = 0.f, P3 = 0.f;
    float Q1 = 0.f, Q2 = 0.f, Q3 = 0.f;
    float R0 = 0.f;

    auto vox = [&](float a0, float a1, float a2, float a3, int tt, float dv) {
        float m = fmaxf(fmaxf(a0, a1), fmaxf(a2, a3));
        float e = __expf(a0 - m) + __expf(a1 - m) + __expf(a2 - m) + __expf(a3 - m);
        float lse = m + __logf(e);
        float z1 = (tt == 1) ? dv : 0.f;
        float z2 = (tt == 2) ? dv : 0.f;
        float z3 = (tt == 3) ? dv : 0.f;
        mn1 = fminf(mn1, z1); mx1 = fmaxf(mx1, z1);
        mn2 = fminf(mn2, z2); mx2 = fmaxf(mx2, z2);
        mn3 = fminf(mn3, z3); mx3 = fmaxf(mx3, z3);
        float l1 = a1 - lse, l2 = a2 - lse, l3 = a3 - lse;
        P1 += z1 * l1; P2 += z2 * l2; P3 += z3 * l3;
        Q1 += l1; Q2 += l2; Q3 += l3;
        R0 += (tt == 0) ? (a0 - lse) : 0.f;
    };

    // Named (statically-indexed) triple-buffer registers -- rule: runtime-
    // indexed vector arrays land in scratch.
    f32x4 ax0, ax1, ax2, ax3, ad;  i32x4 at;
    f32x4 bx0, bx1, bx2, bx3, bd;  i32x4 bt;
    f32x4 cx0, cx1, cx2, cx3, cd;  i32x4 ct;

#define LOAD6(p, off)                                     \
    p##x0 = *(const f32x4*)(xb0 + (off));                 \
    p##x1 = *(const f32x4*)(xb1 + (off));                 \
    p##x2 = *(const f32x4*)(xb2 + (off));                 \
    p##x3 = *(const f32x4*)(xb3 + (off));                 \
    p##t  = *(const i32x4*)(tb0 + (off));                 \
    p##d  = *(const f32x4*)(db0 + (off));

#define CONSUME(p)                                        \
    vox(p##x0.x, p##x1.x, p##x2.x, p##x3.x, p##t.x, p##d.x); \
    vox(p##x0.y, p##x1.y, p##x2.y, p##x3.y, p##t.y, p##d.y); \
    vox(p##x0.z, p##x1.z, p##x2.z, p##x3.z, p##t.z, p##d.z); \
    vox(p##x0.w, p##x1.w, p##x2.w, p##x3.w, p##t.w, p##d.w);

    const int step = STRIDE * 16;          // byte step per sweep (2 MiB)
    int off = q0 * 16;                     // max ~18.9 MB -> fits int32

    LOAD6(a, off)
    LOAD6(b, off + step)
    LOAD6(c, off + 2 * step)

#pragma unroll 1
    for (int i = 0; i < ITERS; i += 3) {
        CONSUME(a)
        if (i + 3 < ITERS) { LOAD6(a, off + 3 * step) }
        CONSUME(b)
        if (i + 4 < ITERS) { LOAD6(b, off + 4 * step) }
        CONSUME(c)
        if (i + 5 < ITERS) { LOAD6(c, off + 5 * step) }
        off += 3 * step;
    }
#undef LOAD6
#undef CONSUME

    // wave(64) butterfly over the 13 accumulators
    for (int off2 = 32; off2; off2 >>= 1) {
        mn1 = fminf(mn1, __shfl_down(mn1, off2, 64));
        mn2 = fminf(mn2, __shfl_down(mn2, off2, 64));
        mn3 = fminf(mn3, __shfl_down(mn3, off2, 64));
        mx1 = fmaxf(mx1, __shfl_down(mx1, off2, 64));
        mx2 = fmaxf(mx2, __shfl_down(mx2, off2, 64));
        mx3 = fmaxf(mx3, __shfl_down(mx3, off2, 64));
        P1 += __shfl_down(P1, off2, 64);
        P2 += __shfl_down(P2, off2, 64);
        P3 += __shfl_down(P3, off2, 64);
        Q1 += __shfl_down(Q1, off2, 64);
        Q2 += __shfl_down(Q2, off2, 64);
        Q3 += __shfl_down(Q3, off2, 64);
        R0 += __shfl_down(R0, off2, 64);
    }

    __shared__ float sv[4][13];
    const int wid = threadIdx.x >> 6;
    if ((threadIdx.x & 63) == 0) {
        sv[wid][0] = mn1; sv[wid][1] = mn2; sv[wid][2] = mn3;
        sv[wid][3] = mx1; sv[wid][4] = mx2; sv[wid][5] = mx3;
        sv[wid][6] = P1;  sv[wid][7] = P2;  sv[wid][8] = P3;
        sv[wid][9] = Q1;  sv[wid][10] = Q2; sv[wid][11] = Q3;
        sv[wid][12] = R0;
    }
    __syncthreads();
    const int i = threadIdx.x;
    if (i < 13) {
        float v = sv[0][i];
        if (i < 3)      v = fminf(fminf(v, sv[1][i]), fminf(sv[2][i], sv[3][i]));
        else if (i < 6) v = fmaxf(fmaxf(v, sv[1][i]), fmaxf(sv[2][i], sv[3][i]));
        else            v = v + sv[1][i] + sv[2][i] + sv[3][i];
        part[(size_t)blockIdx.x * 16 + i] = v;   // plain store — NO atomics
    }
}

// 512 threads, 1 block: thread t reduces 2 rows of one batch (BPB=512).
// t<256 -> batch 0 rows {lane, lane+256}; t>=256 -> batch 1.
// Waves 0..3 are pure batch-0, waves 4..7 pure batch-1.
__global__ __launch_bounds__(512, 1)
void k_final(const float* __restrict__ part, float* __restrict__ out) {
    const int t = threadIdx.x;
    const int batch = t >> 8;
    const int lane8 = t & 255;

    float mn[3] = {__uint_as_float(INF_BITS), __uint_as_float(INF_BITS), __uint_as_float(INF_BITS)};
    float mx[3] = {0.f, 0.f, 0.f};
    double P[3] = {0, 0, 0}, Q[3] = {0, 0, 0}, R0 = 0;

#pragma unroll
    for (int k = 0; k < 2; k++) {
        const float4* r = (const float4*)(part + (size_t)(batch * BPB + k * 256 + lane8) * 16);
        float4 r0 = r[0];  // mn1 mn2 mn3 mx1
        float4 r1 = r[1];  // mx2 mx3 P1  P2
        float4 r2 = r[2];  // P3  Q1  Q2  Q3
        float4 r3 = r[3];  // R0  -   -   -
        mn[0] = fminf(mn[0], r0.x); mn[1] = fminf(mn[1], r0.y); mn[2] = fminf(mn[2], r0.z);
        mx[0] = fmaxf(mx[0], r0.w); mx[1] = fmaxf(mx[1], r1.x); mx[2] = fmaxf(mx[2], r1.y);
        P[0] += (double)r1.z; P[1] += (double)r1.w; P[2] += (double)r2.x;
        Q[0] += (double)r2.y; Q[1] += (double)r2.z; Q[2] += (double)r2.w;
        R0 += (double)r3.x;
    }

    for (int off = 32; off; off >>= 1) {
#pragma unroll
        for (int j = 0; j < 3; j++) {
            mn[j] = fminf(mn[j], __shfl_down(mn[j], off, 64));
            mx[j] = fmaxf(mx[j], __shfl_down(mx[j], off, 64));
            P[j] += __shfl_down(P[j], off, 64);
            Q[j] += __shfl_down(Q[j], off, 64);
        }
        R0 += __shfl_down(R0, off, 64);
    }

    __shared__ float smn[8][3], smx[8][3];
    __shared__ double sP[8][3], sQ[8][3], sR[8];
    const int wid = t >> 6;   // waves 0..3 = batch 0, waves 4..7 = batch 1
    if ((t & 63) == 0) {
#pragma unroll
        for (int j = 0; j < 3; j++) {
            smn[wid][j] = mn[j]; smx[wid][j] = mx[j];
            sP[wid][j] = P[j];   sQ[wid][j] = Q[j];
        }
        sR[wid] = R0;
    }
    __syncthreads();
    if (t == 0) {
        double acc = 0.0;
#pragma unroll
        for (int b = 0; b < 2; b++) {
            double Pb[3] = {0, 0, 0}, Qb[3] = {0, 0, 0};
            float mnb[3], mxb[3];
#pragma unroll
            for (int j = 0; j < 3; j++) { mnb[j] = __uint_as_float(INF_BITS); mxb[j] = 0.f; }
#pragma unroll
            for (int w = 4 * b; w < 4 * b + 4; w++) {
                acc += sR[w];
#pragma unroll
                for (int j = 0; j < 3; j++) {
                    mnb[j] = fminf(mnb[j], smn[w][j]);
                    mxb[j] = fmaxf(mxb[j], smx[w][j]);
                    Pb[j] += sP[w][j];
                    Qb[j] += sQ[w][j];
                }
            }
#pragma unroll
            for (int j = 0; j < 3; j++) {
                float sf = 1.0f / (mxb[j] + EPSF - mnb[j]);   // mirror reference fp32 scale
                acc += (double)sf * (Pb[j] - (double)mnb[j] * Qb[j]);
            }
        }
        out[0] = (float)(-acc / (double)NTOT);
    }
}

extern "C" void kernel_launch(void* const* d_in, const int* in_sizes, int n_in,
                              void* d_out, int out_size, void* d_ws, size_t ws_size,
                              hipStream_t stream) {
    const float* net = (const float*)d_in[0];   // [B, C, D, H, W] fp32
    const int* tgt = (const int*)d_in[1];       // [B, 1, D, H, W] int
    const float* dist = (const float*)d_in[2];  // [B, D, H, W] fp32
    float* part = (float*)d_ws;                 // 1024 x 16 floats = 64 KB

    k_fused<<<BLOCKS, TPB, 0, stream>>>(net, tgt, dist, part);
    k_final<<<1, 512, 0, stream>>>(part, (float*)d_out);
}

// Round 4
// 247.721 us; speedup vs baseline: 1.0901x; 1.0901x over previous
//
#include <hip/hip_runtime.h>

// Problem shape (fixed by setup_inputs): B=2, C=4, D=128, H=192, W=192
#define NB 2
#define NS (128 * 192 * 192)      // spatial voxels per batch = 4718592
#define NTOT (NB * NS)            // 9437184
#define NSQ (NS / 4)              // float4-quads per batch = 1179648
#define EPSF 1e-8f
#define INF_BITS 0x7F800000u

// Geometry: 1536 blocks = 6 blocks/CU = 24 waves/CU (matches waves_per_eu max=6).
#define TPB 256
#define BPB 768                    // blocks per batch
#define BLOCKS (2 * BPB)           // 1536
#define STRIDE (BPB * TPB)         // 196608 quads per sweep
#define ITERS (NSQ / STRIDE)       // exactly 6

// Decomposition: loss = -(R0 + sum_{b,j} s_bj*(P_bj - mn_bj*Q_bj)) / NTOT
//   P_bj = sum z_j*(a_j-lse), Q_bj = sum (a_j-lse), R0 = sum (t==0)*(a_0-lse)
// part layout: 16 floats per block: [0..2]=mn [3..5]=mx [6..8]=P [9..11]=Q [12]=R0

// R12: PURE REVERT to the session-best R9 configuration (wall 248.6 us,
// k_fused ~= 71.6 us by wall subtraction). R10 (cached loads + A/B dbuf,
// 88.5us) and R11 (triple buffer + VGPR headroom, 92us) both REGRESSED
// k_fused vs R9 -- the NT rotating pipeline at 24 waves/CU is the proven
// best. This round re-anchors and collects R9-config counters (never seen:
// R9's k_fused was faster than the 87us poison fills, so it missed top-5).

typedef float __attribute__((ext_vector_type(4))) f32x4;
typedef int   __attribute__((ext_vector_type(4))) i32x4;

__device__ __forceinline__ f32x4 ldnt_f4(const float* p) {
    return __builtin_nontemporal_load((const f32x4*)p);
}
__device__ __forceinline__ i32x4 ldnt_i4(const int* p) {
    return __builtin_nontemporal_load((const i32x4*)p);
}

// waves_per_eu(2,6): max=6 -> VGPR budget ~84 (pipeline needs ~56, fits; keeps
// the allocator from register-starving as in R6), 1.5x the TLP of R9's (2,4).
__global__ __launch_bounds__(TPB)
__attribute__((amdgpu_waves_per_eu(2, 6)))
void k_fused(const float* __restrict__ x,
             const int* __restrict__ tgt,
             const float* __restrict__ dist,
             float* __restrict__ part) {
    const int b = (blockIdx.x >= BPB) ? 1 : 0;
    const int bid = blockIdx.x - b * BPB;
    const int q0 = bid * TPB + threadIdx.x;

    const float* xb = x + (size_t)b * 4 * NSQ * 4;   // batch base (floats)
    const int*   tb = tgt + (size_t)b * NSQ * 4;
    const float* db = dist + (size_t)b * NSQ * 4;

    float mn1 = __uint_as_float(INF_BITS), mn2 = mn1, mn3 = mn1;
    float mx1 = 0.f, mx2 = 0.f, mx3 = 0.f;
    float P1 = 0.f, P2 = 0.f, P3 = 0.f;
    float Q1 = 0.f, Q2 = 0.f, Q3 = 0.f;
    float R0 = 0.f;

    auto vox = [&](float a0, float a1, float a2, float a3, int tt, float dv) {
        float m = fmaxf(fmaxf(a0, a1), fmaxf(a2, a3));
        float e = __expf(a0 - m) + __expf(a1 - m) + __expf(a2 - m) + __expf(a3 - m);
        float lse = m + __logf(e);
        float z1 = (tt == 1) ? dv : 0.f;
        float z2 = (tt == 2) ? dv : 0.f;
        float z3 = (tt == 3) ? dv : 0.f;
        mn1 = fminf(mn1, z1); mx1 = fmaxf(mx1, z1);
        mn2 = fminf(mn2, z2); mx2 = fmaxf(mx2, z2);
        mn3 = fminf(mn3, z3); mx3 = fmaxf(mx3, z3);
        float l1 = a1 - lse, l2 = a2 - lse, l3 = a3 - lse;
        P1 += z1 * l1; P2 += z2 * l2; P3 += z3 * l3;
        Q1 += l1; Q2 += l2; Q3 += l3;
        R0 += (tt == 0) ? (a0 - lse) : 0.f;
    };

    // Rotating-register pipeline with non-temporal streamed loads (R9).
    f32x4 cx0 = ldnt_f4(xb + (size_t)q0 * 4);
    f32x4 cx1 = ldnt_f4(xb + (size_t)(q0 + NSQ) * 4);
    f32x4 cx2 = ldnt_f4(xb + (size_t)(q0 + 2 * NSQ) * 4);
    f32x4 cx3 = ldnt_f4(xb + (size_t)(q0 + 3 * NSQ) * 4);
    i32x4 ct  = ldnt_i4(tb + (size_t)q0 * 4);
    f32x4 cd  = ldnt_f4(db + (size_t)q0 * 4);

#pragma unroll 1
    for (int i = 0; i < ITERS; i++) {
        f32x4 nx0, nx1, nx2, nx3, nd;
        i32x4 nt;
        if (i + 1 < ITERS) {
            const int qn = q0 + (i + 1) * STRIDE;
            nx0 = ldnt_f4(xb + (size_t)qn * 4);
            nx1 = ldnt_f4(xb + (size_t)(qn + NSQ) * 4);
            nx2 = ldnt_f4(xb + (size_t)(qn + 2 * NSQ) * 4);
            nx3 = ldnt_f4(xb + (size_t)(qn + 3 * NSQ) * 4);
            nt  = ldnt_i4(tb + (size_t)qn * 4);
            nd  = ldnt_f4(db + (size_t)qn * 4);
        }
        vox(cx0.x, cx1.x, cx2.x, cx3.x, ct.x, cd.x);
        vox(cx0.y, cx1.y, cx2.y, cx3.y, ct.y, cd.y);
        vox(cx0.z, cx1.z, cx2.z, cx3.z, ct.z, cd.z);
        vox(cx0.w, cx1.w, cx2.w, cx3.w, ct.w, cd.w);
        if (i + 1 < ITERS) {
            cx0 = nx0; cx1 = nx1; cx2 = nx2; cx3 = nx3; ct = nt; cd = nd;
        }
    }

    // wave(64) butterfly over the 13 accumulators
    for (int off = 32; off; off >>= 1) {
        mn1 = fminf(mn1, __shfl_down(mn1, off, 64));
        mn2 = fminf(mn2, __shfl_down(mn2, off, 64));
        mn3 = fminf(mn3, __shfl_down(mn3, off, 64));
        mx1 = fmaxf(mx1, __shfl_down(mx1, off, 64));
        mx2 = fmaxf(mx2, __shfl_down(mx2, off, 64));
        mx3 = fmaxf(mx3, __shfl_down(mx3, off, 64));
        P1 += __shfl_down(P1, off, 64);
        P2 += __shfl_down(P2, off, 64);
        P3 += __shfl_down(P3, off, 64);
        Q1 += __shfl_down(Q1, off, 64);
        Q2 += __shfl_down(Q2, off, 64);
        Q3 += __shfl_down(Q3, off, 64);
        R0 += __shfl_down(R0, off, 64);
    }

    __shared__ float sv[4][13];
    const int wid = threadIdx.x >> 6;
    if ((threadIdx.x & 63) == 0) {
        sv[wid][0] = mn1; sv[wid][1] = mn2; sv[wid][2] = mn3;
        sv[wid][3] = mx1; sv[wid][4] = mx2; sv[wid][5] = mx3;
        sv[wid][6] = P1;  sv[wid][7] = P2;  sv[wid][8] = P3;
        sv[wid][9] = Q1;  sv[wid][10] = Q2; sv[wid][11] = Q3;
        sv[wid][12] = R0;
    }
    __syncthreads();
    const int i = threadIdx.x;
    if (i < 13) {
        float v = sv[0][i];
        if (i < 3)      v = fminf(fminf(v, sv[1][i]), fminf(sv[2][i], sv[3][i]));
        else if (i < 6) v = fmaxf(fmaxf(v, sv[1][i]), fmaxf(sv[2][i], sv[3][i]));
        else            v = v + sv[1][i] + sv[2][i] + sv[3][i];
        part[(size_t)blockIdx.x * 16 + i] = v;   // plain store — NO atomics
    }
}

// 512 threads, 1 block: thread t reduces 3 rows of one batch.
// t<256 -> batch 0 rows {lane, lane+256, lane+512}; t>=256 -> batch 1 (+768).
// Waves 0..3 are pure batch-0, waves 4..7 pure batch-1.
__global__ __launch_bounds__(512, 1)
void k_final(const float* __restrict__ part, float* __restrict__ out) {
    const int t = threadIdx.x;
    const int batch = t >> 8;
    const int lane8 = t & 255;

    float mn[3] = {__uint_as_float(INF_BITS), __uint_as_float(INF_BITS), __uint_as_float(INF_BITS)};
    float mx[3] = {0.f, 0.f, 0.f};
    double P[3] = {0, 0, 0}, Q[3] = {0, 0, 0}, R0 = 0;

#pragma unroll
    for (int k = 0; k < 3; k++) {
        const float4* r = (const float4*)(part + (size_t)(batch * BPB + k * 256 + lane8) * 16);
        float4 r0 = r[0];  // mn1 mn2 mn3 mx1
        float4 r1 = r[1];  // mx2 mx3 P1  P2
        float4 r2 = r[2];  // P3  Q1  Q2  Q3
        float4 r3 = r[3];  // R0  -   -   -
        mn[0] = fminf(mn[0], r0.x); mn[1] = fminf(mn[1], r0.y); mn[2] = fminf(mn[2], r0.z);
        mx[0] = fmaxf(mx[0], r0.w); mx[1] = fmaxf(mx[1], r1.x); mx[2] = fmaxf(mx[2], r1.y);
        P[0] += (double)r1.z; P[1] += (double)r1.w; P[2] += (double)r2.x;
        Q[0] += (double)r2.y; Q[1] += (double)r2.z; Q[2] += (double)r2.w;
        R0 += (double)r3.x;
    }

    for (int off = 32; off; off >>= 1) {
#pragma unroll
        for (int j = 0; j < 3; j++) {
            mn[j] = fminf(mn[j], __shfl_down(mn[j], off, 64));
            mx[j] = fmaxf(mx[j], __shfl_down(mx[j], off, 64));
            P[j] += __shfl_down(P[j], off, 64);
            Q[j] += __shfl_down(Q[j], off, 64);
        }
        R0 += __shfl_down(R0, off, 64);
    }

    __shared__ float smn[8][3], smx[8][3];
    __shared__ double sP[8][3], sQ[8][3], sR[8];
    const int wid = t >> 6;   // waves 0..3 = batch 0, waves 4..7 = batch 1
    if ((t & 63) == 0) {
#pragma unroll
        for (int j = 0; j < 3; j++) {
            smn[wid][j] = mn[j]; smx[wid][j] = mx[j];
            sP[wid][j] = P[j];   sQ[wid][j] = Q[j];
        }
        sR[wid] = R0;
    }
    __syncthreads();
    if (t == 0) {
        double acc = 0.0;
#pragma unroll
        for (int b = 0; b < 2; b++) {
            double Pb[3] = {0, 0, 0}, Qb[3] = {0, 0, 0};
            float mnb[3], mxb[3];
#pragma unroll
            for (int j = 0; j < 3; j++) { mnb[j] = __uint_as_float(INF_BITS); mxb[j] = 0.f; }
#pragma unroll
            for (int w = 4 * b; w < 4 * b + 4; w++) {
                acc += sR[w];
#pragma unroll
                for (int j = 0; j < 3; j++) {
                    mnb[j] = fminf(mnb[j], smn[w][j]);
                    mxb[j] = fmaxf(mxb[j], smx[w][j]);
                    Pb[j] += sP[w][j];
                    Qb[j] += sQ[w][j];
                }
            }
#pragma unroll
            for (int j = 0; j < 3; j++) {
                float sf = 1.0f / (mxb[j] + EPSF - mnb[j]);   // mirror reference fp32 scale
                acc += (double)sf * (Pb[j] - (double)mnb[j] * Qb[j]);
            }
        }
        out[0] = (float)(-acc / (double)NTOT);
    }
}

extern "C" void kernel_launch(void* const* d_in, const int* in_sizes, int n_in,
                              void* d_out, int out_size, void* d_ws, size_t ws_size,
                              hipStream_t stream) {
    const float* net = (const float*)d_in[0];   // [B, C, D, H, W] fp32
    const int* tgt = (const int*)d_in[1];       // [B, 1, D, H, W] int
    const float* dist = (const float*)d_in[2];  // [B, D, H, W] fp32
    float* part = (float*)d_ws;                 // 1536 x 16 floats = 98 KB

    k_fused<<<BLOCKS, TPB, 0, stream>>>(net, tgt, dist, part);
    k_final<<<1, 512, 0, stream>>>(part, (float*)d_out);
}